// Round 8
// baseline (142.721 us; speedup 1.0000x reference)
//
#include <hip/hip_runtime.h>

// Gaussian pyramid, 4 levels. Input (16,3,1024,1024) f32.
// Level0 copy fused into level-1 reduce. Level k+1 = replicate-pad-2 +
// separable 5x5, stride 2.
//
// R7 lesson: register-window conv loads are half-dense (32B lane stride for
// 16B accesses) -> 2x line transactions in L1/TA; same for copy stores.
// Fix: LDS-stage the input tile with dense loads; copy + conv read from LDS.
//
// Tile: 256 output cols x 8 output rows per block (256 threads, (64,4)).
// Staged input: 19 rows x 520 floats (halo+alignment pad) = 39.5 KB LDS.

__global__ __launch_bounds__(256) void gpyr_reduce_old(
        const float* __restrict__ in, float* __restrict__ out,
        int Hin, int Win, int Hout, int Wout);

template <bool FUSE>
__global__ __launch_bounds__(256) void gpyr_reduce_lds(
        const float* __restrict__ in,
        float* __restrict__ out0,
        float* __restrict__ out1,
        int Hin, int Win, int Hout, int Wout) {
    __shared__ float lds[19][520];

    const int X   = blockIdx.x * 256;   // output col base
    const int Y   = blockIdx.y * 8;     // output row base
    const int img = blockIdx.z;
    const int tid = threadIdx.y * 64 + threadIdx.x;

    const float* ip = in + (size_t)img * Hin * Win;

    // ---- Stage: lds[r][4*c4 .. +3] = im[clamp(2Y-2+r)][clamp(2X-4+4*c4 ..)]
    // Dense: consecutive tid -> consecutive c4 -> 16B lane stride.
    for (int idx = tid; idx < 19 * 130; idx += 256) {
        const int r  = idx / 130;
        const int c4 = idx % 130;
        const int iy = min(max(2 * Y - 2 + r, 0), Hin - 1);
        const int gx = 2 * X - 4 + 4 * c4;
        const float* rowp = ip + (size_t)iy * Win;
        float4 val;
        if (gx >= 0 && gx + 4 <= Win) {
            val = *(const float4*)(rowp + gx);
        } else {
            // only first/last c4 of edge blocks: replicate boundary value
            val.x = rowp[min(max(gx + 0, 0), Win - 1)];
            val.y = rowp[min(max(gx + 1, 0), Win - 1)];
            val.z = rowp[min(max(gx + 2, 0), Win - 1)];
            val.w = rowp[min(max(gx + 3, 0), Win - 1)];
        }
        *(float4*)&lds[r][4 * c4] = val;
    }
    __syncthreads();

    // ---- out0 copy from LDS (dense reads, dense stores).
    if (FUSE) {
        float* op = out0 + (size_t)img * Hin * Win;
        for (int idx = tid; idx < 16 * 128; idx += 256) {
            const int r  = idx / 128;           // wave = exactly half a row
            const int c4 = idx % 128;
            float4 val = *(const float4*)&lds[2 + r][4 + 4 * c4];
            *(float4*)(op + (size_t)(2 * Y + r) * Win + 2 * X + 4 * c4) = val;
        }
    }

    // ---- Conv: thread (tx,ty) -> output cols X+4tx..+3, rows Y+2ty, Y+2ty+1.
    const int tx = threadIdx.x, ty = threadIdx.y;
    const float k0 = 0.0625f, k1 = 0.25f, k2 = 0.375f;
    const float kk[5] = {k0, k1, k2, k1, k0};

    float v0[11], v1[11];
#pragma unroll
    for (int i = 0; i < 11; ++i) { v0[i] = 0.0f; v1[i] = 0.0f; }

#pragma unroll
    for (int s = 0; s < 7; ++s) {
        const float* lp = &lds[4 * ty + s][8 * tx];
        float4 A = *(const float4*)(lp);
        float4 B = *(const float4*)(lp + 4);
        float4 C = *(const float4*)(lp + 8);
        float4 D = *(const float4*)(lp + 12);
        const float x0 = A.z, x1 = A.w, x2 = B.x, x3 = B.y, x4 = B.z, x5 = B.w,
                    x6 = C.x, x7 = C.y, x8 = C.z, x9 = C.w, x10 = D.x;
        if (s <= 4) {
            const float w = kk[s];
            v0[0] += w * x0; v0[1] += w * x1; v0[2] += w * x2; v0[3] += w * x3;
            v0[4] += w * x4; v0[5] += w * x5; v0[6] += w * x6; v0[7] += w * x7;
            v0[8] += w * x8; v0[9] += w * x9; v0[10] += w * x10;
        }
        if (s >= 2) {
            const float w = kk[s - 2];
            v1[0] += w * x0; v1[1] += w * x1; v1[2] += w * x2; v1[3] += w * x3;
            v1[4] += w * x4; v1[5] += w * x5; v1[6] += w * x6; v1[7] += w * x7;
            v1[8] += w * x8; v1[9] += w * x9; v1[10] += w * x10;
        }
    }

    float* o1p = out1 + (size_t)img * Hout * Wout;
    {
        float4 o;
        o.x = k0 * v0[0] + k1 * v0[1] + k2 * v0[2] + k1 * v0[3] + k0 * v0[4];
        o.y = k0 * v0[2] + k1 * v0[3] + k2 * v0[4] + k1 * v0[5] + k0 * v0[6];
        o.z = k0 * v0[4] + k1 * v0[5] + k2 * v0[6] + k1 * v0[7] + k0 * v0[8];
        o.w = k0 * v0[6] + k1 * v0[7] + k2 * v0[8] + k1 * v0[9] + k0 * v0[10];
        *(float4*)(o1p + (size_t)(Y + 2 * ty) * Wout + X + 4 * tx) = o;
    }
    {
        float4 o;
        o.x = k0 * v1[0] + k1 * v1[1] + k2 * v1[2] + k1 * v1[3] + k0 * v1[4];
        o.y = k0 * v1[2] + k1 * v1[3] + k2 * v1[4] + k1 * v1[5] + k0 * v1[6];
        o.z = k0 * v1[4] + k1 * v1[5] + k2 * v1[6] + k1 * v1[7] + k0 * v1[8];
        o.w = k0 * v1[6] + k1 * v1[7] + k2 * v1[8] + k1 * v1[9] + k0 * v1[10];
        *(float4*)(o1p + (size_t)(Y + 2 * ty + 1) * Wout + X + 4 * tx) = o;
    }
}

// Old select-based kernel for the tiny level 3 (128x128).
__device__ __forceinline__ float Ssel(bool l, bool r, float L, float I, float R) {
    return l ? L : (r ? R : I);
}

__global__ __launch_bounds__(256) void gpyr_reduce_old(
        const float* __restrict__ in, float* __restrict__ out,
        int Hin, int Win, int Hout, int Wout) {
    const int ox0 = (blockIdx.x * blockDim.x + threadIdx.x) * 4;
    const int oy  = blockIdx.y * blockDim.y + threadIdx.y;
    const int img = blockIdx.z;
    if (ox0 >= Wout || oy >= Hout) return;

    const float k0 = 0.0625f, k1 = 0.25f, k2 = 0.375f;
    const float kk[5] = {k0, k1, k2, k1, k0};

    const bool left  = (ox0 == 0);
    const bool right = (2 * ox0 + 12 > Win);
    int xb = 2 * ox0 - 4;
    if (left)  xb = 0;
    if (right) xb = Win - 16;

    const float* ip = in + (size_t)img * Hin * Win;

    float v[11];
#pragma unroll
    for (int i = 0; i < 11; ++i) v[i] = 0.0f;

#pragma unroll
    for (int ky = 0; ky < 5; ++ky) {
        int iy = 2 * oy + ky - 2;
        iy = min(max(iy, 0), Hin - 1);
        const float4* rp4 = (const float4*)(ip + (size_t)iy * Win + xb);
        float4 A = rp4[0], B = rp4[1], C = rp4[2], D = rp4[3];
        const float w = kk[ky];
        v[0]  += w * Ssel(left, right, A.x, A.z, B.z);
        v[1]  += w * Ssel(left, right, A.x, A.w, B.w);
        v[2]  += w * Ssel(left, right, A.x, B.x, C.x);
        v[3]  += w * Ssel(left, right, A.y, B.y, C.y);
        v[4]  += w * Ssel(left, right, A.z, B.z, C.z);
        v[5]  += w * Ssel(left, right, A.w, B.w, C.w);
        v[6]  += w * Ssel(left, right, B.x, C.x, D.x);
        v[7]  += w * Ssel(left, right, B.y, C.y, D.y);
        v[8]  += w * Ssel(left, right, B.z, C.z, D.z);
        v[9]  += w * Ssel(left, right, B.w, C.w, D.w);
        v[10] += w * Ssel(left, right, C.x, D.x, D.w);
    }

    float4 o;
    o.x = k0 * v[0] + k1 * v[1] + k2 * v[2] + k1 * v[3] + k0 * v[4];
    o.y = k0 * v[2] + k1 * v[3] + k2 * v[4] + k1 * v[5] + k0 * v[6];
    o.z = k0 * v[4] + k1 * v[5] + k2 * v[6] + k1 * v[7] + k0 * v[8];
    o.w = k0 * v[6] + k1 * v[7] + k2 * v[8] + k1 * v[9] + k0 * v[10];

    *(float4*)(out + (size_t)img * Hout * Wout + (size_t)oy * Wout + ox0) = o;
}

extern "C" void kernel_launch(void* const* d_in, const int* in_sizes, int n_in,
                              void* d_out, int out_size, void* d_ws, size_t ws_size,
                              hipStream_t stream) {
    const float* im = (const float*)d_in[0];
    float* out = (float*)d_out;

    const int NC = 16 * 3;
    const size_t L0 = (size_t)NC * 1024 * 1024;
    const size_t L1 = (size_t)NC * 512 * 512;
    const size_t L2 = (size_t)NC * 256 * 256;

    float* out0 = out;
    float* out1 = out0 + L0;
    float* out2 = out1 + L1;
    float* out3 = out2 + L2;

    // Fused level0 copy + level1 reduce (LDS-staged).
    {
        dim3 block(64, 4, 1);
        dim3 grid(512 / 256, 512 / 8, NC);   // (2, 64, 48)
        gpyr_reduce_lds<true><<<grid, block, 0, stream>>>(im, out0, out1, 1024, 1024, 512, 512);
    }
    // Level 2 (LDS-staged, tile = full width).
    {
        dim3 block(64, 4, 1);
        dim3 grid(256 / 256, 256 / 8, NC);   // (1, 32, 48)
        gpyr_reduce_lds<false><<<grid, block, 0, stream>>>(out1, nullptr, out2, 512, 512, 256, 256);
    }
    // Level 3 (tiny): old register kernel.
    {
        dim3 block(32, 8, 1);
        dim3 grid(1, 16, NC);                // 128/4/32=1, 128/8=16
        gpyr_reduce_old<<<grid, block, 0, stream>>>(out2, out3, 256, 256, 128, 128);
    }
}

// Round 9
// 129.858 us; speedup vs baseline: 1.0991x; 1.0991x over previous
//
#include <hip/hip_runtime.h>

// Gaussian pyramid, 4 levels. Input (16,3,1024,1024) f32.
// Level0 copy fused into level-1 reduce. Level k+1 = replicate-pad-2 +
// separable 5x5, stride 2.
//
// R8 lesson: one-shot kernels are latency-bound (each wave pays ~900cyc cold
// latency once for ~300cyc of work). Fix: vertical sliding window — each
// thread produces R consecutive output rows, keeping a 5-row ring of
// horizontally-convolved values in registers. 2 new input rows per output row
// (vs 5), loop-level ILP, copy fused from registers.

__device__ __forceinline__ float S(bool l, bool r, float L, float I, float R_) {
    return l ? L : (r ? R_ : I);
}
__device__ __forceinline__ float4 S4(bool l, bool r, const float4& L, const float4& I, const float4& R_) {
    float4 o;
    o.x = S(l, r, L.x, I.x, R_.x);
    o.y = S(l, r, L.y, I.y, R_.y);
    o.z = S(l, r, L.z, I.z, R_.z);
    o.w = S(l, r, L.w, I.w, R_.w);
    return o;
}

struct Row { float4 A, B, C, D; };

__device__ __forceinline__ Row loadrow(const float* ip, int iy, int Win, int xb) {
    const float4* p = (const float4*)(ip + (size_t)iy * Win + xb);
    Row r; r.A = p[0]; r.B = p[1]; r.C = p[2]; r.D = p[3];
    return r;
}

// Horizontal 5-tap on one staged row -> 4 outputs (stride-2 phase).
__device__ __forceinline__ float4 hconv(const Row& rw, bool left, bool right) {
    const float k0 = 0.0625f, k1 = 0.25f, k2 = 0.375f;
    // v[i] = input x = 2*ox0-2+i (replicate-clamped via selects)
    float v0  = S(left, right, rw.A.x, rw.A.z, rw.B.z);
    float v1  = S(left, right, rw.A.x, rw.A.w, rw.B.w);
    float v2  = S(left, right, rw.A.x, rw.B.x, rw.C.x);
    float v3  = S(left, right, rw.A.y, rw.B.y, rw.C.y);
    float v4  = S(left, right, rw.A.z, rw.B.z, rw.C.z);
    float v5  = S(left, right, rw.A.w, rw.B.w, rw.C.w);
    float v6  = S(left, right, rw.B.x, rw.C.x, rw.D.x);
    float v7  = S(left, right, rw.B.y, rw.C.y, rw.D.y);
    float v8  = S(left, right, rw.B.z, rw.C.z, rw.D.z);
    float v9  = S(left, right, rw.B.w, rw.C.w, rw.D.w);
    float v10 = S(left, right, rw.C.x, rw.D.x, rw.D.w);
    float4 h;
    h.x = k0 * (v0 + v4)  + k1 * (v1 + v3) + k2 * v2;
    h.y = k0 * (v2 + v6)  + k1 * (v3 + v5) + k2 * v4;
    h.z = k0 * (v4 + v8)  + k1 * (v5 + v7) + k2 * v6;
    h.w = k0 * (v6 + v10) + k1 * (v7 + v9) + k2 * v8;
    return h;
}

template <bool FUSE>
__global__ __launch_bounds__(256) void gpyr_slide(
        const float* __restrict__ in,
        float* __restrict__ out0,
        float* __restrict__ out1,
        int Hin, int Win, int Hout, int Wout, int R) {
    const int tx = threadIdx.x, ty = threadIdx.y;
    const int ox0 = (blockIdx.x * blockDim.x + tx) * 4;
    const int Y0  = (blockIdx.y * blockDim.y + ty) * R;
    const int img = blockIdx.z;
    if (ox0 >= Wout) return;

    const bool left  = (ox0 == 0);
    const bool right = (2 * ox0 + 12 > Win);
    int xb = 2 * ox0 - 4;
    if (left)  xb = 0;
    if (right) xb = Win - 16;

    const float* ip = in + (size_t)img * Hin * Win;
    float* o1 = out1 + (size_t)img * Hout * Wout;
    float* o0 = FUSE ? out0 + (size_t)img * Hin * Win : nullptr;

    // Prologue: rows 2Y0-2, 2Y0-1, 2Y0.
    Row r0 = loadrow(ip, max(2 * Y0 - 2, 0), Win, xb);
    Row r1 = loadrow(ip, max(2 * Y0 - 1, 0), Win, xb);
    Row r2 = loadrow(ip, 2 * Y0, Win, xb);
    float4 hs0 = hconv(r0, left, right);
    float4 hs1 = hconv(r1, left, right);
    float4 hs2 = hconv(r2, left, right);
    // pending copy regs for even row 2Y0 (mid 8 floats of r2)
    float4 qlo = S4(left, right, r2.A, r2.B, r2.C);
    float4 qhi = S4(left, right, r2.B, r2.C, r2.D);

    const float k0 = 0.0625f, k1 = 0.25f, k2 = 0.375f;

    for (int i = 0; i < R; ++i) {
        const int oy = Y0 + i;
        // issue the 2 new rows' loads
        Row ra = loadrow(ip, min(2 * oy + 1, Hin - 1), Win, xb);
        Row rb = loadrow(ip, min(2 * oy + 2, Hin - 1), Win, xb);

        // copy-store even row 2*oy from saved regs (independent of loads)
        if (FUSE) {
            float* op = o0 + (size_t)(2 * oy) * Win + 2 * ox0;
            *(float4*)(op)     = qlo;
            *(float4*)(op + 4) = qhi;
        }

        float4 ha = hconv(ra, left, right);
        if (FUSE) {
            float4 alo = S4(left, right, ra.A, ra.B, ra.C);
            float4 ahi = S4(left, right, ra.B, ra.C, ra.D);
            float* op = o0 + (size_t)(2 * oy + 1) * Win + 2 * ox0;
            *(float4*)(op)     = alo;
            *(float4*)(op + 4) = ahi;
        }

        float4 hb = hconv(rb, left, right);
        qlo = S4(left, right, rb.A, rb.B, rb.C);   // row 2*oy+2 = next even row
        qhi = S4(left, right, rb.B, rb.C, rb.D);

        float4 o;
        o.x = k0 * (hs0.x + hb.x) + k1 * (hs1.x + ha.x) + k2 * hs2.x;
        o.y = k0 * (hs0.y + hb.y) + k1 * (hs1.y + ha.y) + k2 * hs2.y;
        o.z = k0 * (hs0.z + hb.z) + k1 * (hs1.z + ha.z) + k2 * hs2.z;
        o.w = k0 * (hs0.w + hb.w) + k1 * (hs1.w + ha.w) + k2 * hs2.w;
        *(float4*)(o1 + (size_t)oy * Wout + ox0) = o;

        hs0 = hs2; hs1 = ha; hs2 = hb;  // slide by 2 input rows
    }
}

extern "C" void kernel_launch(void* const* d_in, const int* in_sizes, int n_in,
                              void* d_out, int out_size, void* d_ws, size_t ws_size,
                              hipStream_t stream) {
    const float* im = (const float*)d_in[0];
    float* out = (float*)d_out;

    const int NC = 16 * 3;
    const size_t L0 = (size_t)NC * 1024 * 1024;
    const size_t L1 = (size_t)NC * 512 * 512;
    const size_t L2 = (size_t)NC * 256 * 256;

    float* out0 = out;
    float* out1 = out0 + L0;
    float* out2 = out1 + L1;
    float* out3 = out2 + L2;

    // Level 0+1 fused: 512x512 out, R=8 rows/thread.
    {
        dim3 block(64, 4, 1);
        dim3 grid(2, 512 / (4 * 8), NC);       // (2, 16, 48)
        gpyr_slide<true><<<grid, block, 0, stream>>>(im, out0, out1, 1024, 1024, 512, 512, 8);
    }
    // Level 2: 256x256 out, R=4.
    {
        dim3 block(64, 4, 1);
        dim3 grid(1, 256 / (4 * 4), NC);       // (1, 16, 48)
        gpyr_slide<false><<<grid, block, 0, stream>>>(out1, nullptr, out2, 512, 512, 256, 256, 4);
    }
    // Level 3: 128x128 out, R=2.
    {
        dim3 block(32, 8, 1);
        dim3 grid(1, 128 / (8 * 2), NC);       // (1, 8, 48)
        gpyr_slide<false><<<grid, block, 0, stream>>>(out2, nullptr, out3, 256, 256, 128, 128, 2);
    }
}

// Round 10
// 128.898 us; speedup vs baseline: 1.1072x; 1.0074x over previous
//
#include <hip/hip_runtime.h>

// Gaussian pyramid, 4 levels. Input (16,3,1024,1024) f32.
// Level0 copy fused into level-1 reduce. Level k+1 = replicate-pad-2 +
// separable 5x5, stride 2.
//
// R9 lesson: runtime row-count R blocked loop unrolling -> loads of iter i+1
// couldn't issue before iter i's compute (MLP capped at 8 loads/wave).
// Fix: compile-time R/HIN/WIN + full unroll -> software-pipelined loads,
// immediate-offset address folding.

__device__ __forceinline__ float S(bool l, bool r, float L, float I, float R_) {
    return l ? L : (r ? R_ : I);
}
__device__ __forceinline__ float4 S4(bool l, bool r, const float4& L, const float4& I, const float4& R_) {
    float4 o;
    o.x = S(l, r, L.x, I.x, R_.x);
    o.y = S(l, r, L.y, I.y, R_.y);
    o.z = S(l, r, L.z, I.z, R_.z);
    o.w = S(l, r, L.w, I.w, R_.w);
    return o;
}

struct Row { float4 A, B, C, D; };

template <int WIN>
__device__ __forceinline__ Row loadrow(const float* ip, int iy, int xb) {
    const float4* p = (const float4*)(ip + (size_t)iy * WIN + xb);
    Row r; r.A = p[0]; r.B = p[1]; r.C = p[2]; r.D = p[3];
    return r;
}

// Horizontal 5-tap on one staged row -> 4 outputs (stride-2 phase).
__device__ __forceinline__ float4 hconv(const Row& rw, bool left, bool right) {
    const float k0 = 0.0625f, k1 = 0.25f, k2 = 0.375f;
    float v0  = S(left, right, rw.A.x, rw.A.z, rw.B.z);
    float v1  = S(left, right, rw.A.x, rw.A.w, rw.B.w);
    float v2  = S(left, right, rw.A.x, rw.B.x, rw.C.x);
    float v3  = S(left, right, rw.A.y, rw.B.y, rw.C.y);
    float v4  = S(left, right, rw.A.z, rw.B.z, rw.C.z);
    float v5  = S(left, right, rw.A.w, rw.B.w, rw.C.w);
    float v6  = S(left, right, rw.B.x, rw.C.x, rw.D.x);
    float v7  = S(left, right, rw.B.y, rw.C.y, rw.D.y);
    float v8  = S(left, right, rw.B.z, rw.C.z, rw.D.z);
    float v9  = S(left, right, rw.B.w, rw.C.w, rw.D.w);
    float v10 = S(left, right, rw.C.x, rw.D.x, rw.D.w);
    float4 h;
    h.x = k0 * (v0 + v4)  + k1 * (v1 + v3) + k2 * v2;
    h.y = k0 * (v2 + v6)  + k1 * (v3 + v5) + k2 * v4;
    h.z = k0 * (v4 + v8)  + k1 * (v5 + v7) + k2 * v6;
    h.w = k0 * (v6 + v10) + k1 * (v7 + v9) + k2 * v8;
    return h;
}

template <int R, int HIN, int WIN, bool FUSE>
__global__ __launch_bounds__(256) void gpyr_slide(
        const float* __restrict__ in,
        float* __restrict__ out0,
        float* __restrict__ out1) {
    constexpr int HOUT = HIN / 2, WOUT = WIN / 2;
    const int tx = threadIdx.x, ty = threadIdx.y;
    const int ox0 = (blockIdx.x * blockDim.x + tx) * 4;
    const int Y0  = (blockIdx.y * blockDim.y + ty) * R;
    const int img = blockIdx.z;

    const bool left  = (ox0 == 0);
    const bool right = (2 * ox0 + 12 > WIN);
    int xb = 2 * ox0 - 4;
    if (left)  xb = 0;
    if (right) xb = WIN - 16;

    const float* ip = in + (size_t)img * HIN * WIN;
    float* o1 = out1 + (size_t)img * HOUT * WOUT;
    float* o0 = FUSE ? out0 + (size_t)img * HIN * WIN : nullptr;

    // Prologue: rows 2Y0-2, 2Y0-1, 2Y0.
    Row r0 = loadrow<WIN>(ip, max(2 * Y0 - 2, 0), xb);
    Row r1 = loadrow<WIN>(ip, max(2 * Y0 - 1, 0), xb);
    Row r2 = loadrow<WIN>(ip, 2 * Y0, xb);
    float4 hs0 = hconv(r0, left, right);
    float4 hs1 = hconv(r1, left, right);
    float4 hs2 = hconv(r2, left, right);
    float4 qlo = S4(left, right, r2.A, r2.B, r2.C);
    float4 qhi = S4(left, right, r2.B, r2.C, r2.D);

    const float k0 = 0.0625f, k1 = 0.25f, k2 = 0.375f;

#pragma unroll
    for (int i = 0; i < R; ++i) {
        const int oy = Y0 + i;
        Row ra = loadrow<WIN>(ip, min(2 * oy + 1, HIN - 1), xb);
        Row rb = loadrow<WIN>(ip, min(2 * oy + 2, HIN - 1), xb);

        if (FUSE) {
            float* op = o0 + (size_t)(2 * oy) * WIN + 2 * ox0;
            *(float4*)(op)     = qlo;
            *(float4*)(op + 4) = qhi;
        }

        float4 ha = hconv(ra, left, right);
        if (FUSE) {
            float4 alo = S4(left, right, ra.A, ra.B, ra.C);
            float4 ahi = S4(left, right, ra.B, ra.C, ra.D);
            float* op = o0 + (size_t)(2 * oy + 1) * WIN + 2 * ox0;
            *(float4*)(op)     = alo;
            *(float4*)(op + 4) = ahi;
        }

        float4 hb = hconv(rb, left, right);
        qlo = S4(left, right, rb.A, rb.B, rb.C);
        qhi = S4(left, right, rb.B, rb.C, rb.D);

        float4 o;
        o.x = k0 * (hs0.x + hb.x) + k1 * (hs1.x + ha.x) + k2 * hs2.x;
        o.y = k0 * (hs0.y + hb.y) + k1 * (hs1.y + ha.y) + k2 * hs2.y;
        o.z = k0 * (hs0.z + hb.z) + k1 * (hs1.z + ha.z) + k2 * hs2.z;
        o.w = k0 * (hs0.w + hb.w) + k1 * (hs1.w + ha.w) + k2 * hs2.w;
        *(float4*)(o1 + (size_t)oy * WOUT + ox0) = o;

        hs0 = hs2; hs1 = ha; hs2 = hb;
    }
}

extern "C" void kernel_launch(void* const* d_in, const int* in_sizes, int n_in,
                              void* d_out, int out_size, void* d_ws, size_t ws_size,
                              hipStream_t stream) {
    const float* im = (const float*)d_in[0];
    float* out = (float*)d_out;

    const int NC = 16 * 3;
    const size_t L0 = (size_t)NC * 1024 * 1024;
    const size_t L1 = (size_t)NC * 512 * 512;
    const size_t L2 = (size_t)NC * 256 * 256;

    float* out0 = out;
    float* out1 = out0 + L0;
    float* out2 = out1 + L1;
    float* out3 = out2 + L2;

    // Level 0+1 fused: 512x512 out, R=8 rows/thread.
    {
        dim3 block(64, 4, 1);
        dim3 grid(2, 512 / (4 * 8), NC);       // (2, 16, 48)
        gpyr_slide<8, 1024, 1024, true><<<grid, block, 0, stream>>>(im, out0, out1);
    }
    // Level 2: 256x256 out, R=4.
    {
        dim3 block(64, 4, 1);
        dim3 grid(1, 256 / (4 * 4), NC);       // (1, 16, 48)
        gpyr_slide<4, 512, 512, false><<<grid, block, 0, stream>>>(out1, nullptr, out2);
    }
    // Level 3: 128x128 out, R=2.
    {
        dim3 block(32, 8, 1);
        dim3 grid(1, 128 / (8 * 2), NC);       // (1, 8, 48)
        gpyr_slide<2, 256, 256, false><<<grid, block, 0, stream>>>(out2, nullptr, out3);
    }
}

// Round 11
// 126.005 us; speedup vs baseline: 1.1327x; 1.0230x over previous
//
#include <hip/hip_runtime.h>

// Gaussian pyramid, 4 levels. Input (16,3,1024,1024) f32.
// Level0 copy fused into level-1 reduce. Level k+1 = replicate-pad-2 +
// separable 5x5, stride 2.
//
// R10 lesson: full unroll alone did NOT pipeline loads across iterations
// (stores + immediate consumption pinned the waitcnt right after issue).
// R11: (1) EXPLICIT 1-iter prefetch — next rows load into dedicated regs
// before current rows are consumed; (2) remap-once edge handling — one
// select pass per loaded row, then select-free conv wiring + copy.

struct Row { float4 A, B, C, D; };

template <int WIN>
__device__ __forceinline__ Row loadrow(const float* ip, int iy, int xb) {
    const float4* p = (const float4*)(ip + (size_t)iy * WIN + xb);
    Row r; r.A = p[0]; r.B = p[1]; r.C = p[2]; r.D = p[3];
    return r;
}

// In-place remap so that INTERIOR register wiring is correct at image edges
// (replicate padding). left: virtual window = [bcast(A.x), A, B, C];
// right: [B, C, D, bcast(D.w)]. Only components consumed downstream are
// remapped (A.z, A.w, B.*, C.*, D.x).
__device__ __forceinline__ void remap(Row& w, bool l, bool r) {
    const float4 A = w.A, B = w.B, C = w.C, D = w.D;
    w.A.z = l ? A.x : (r ? B.z : A.z);
    w.A.w = l ? A.x : (r ? B.w : A.w);
    w.B.x = l ? A.x : (r ? C.x : B.x);
    w.B.y = l ? A.y : (r ? C.y : B.y);
    w.B.z = l ? A.z : (r ? C.z : B.z);
    w.B.w = l ? A.w : (r ? C.w : B.w);
    w.C.x = l ? B.x : (r ? D.x : C.x);
    w.C.y = l ? B.y : (r ? D.y : C.y);
    w.C.z = l ? B.z : (r ? D.z : C.z);
    w.C.w = l ? B.w : (r ? D.w : C.w);
    w.D.x = l ? C.x : (r ? D.w : D.x);
}

// Select-free horizontal 5-tap (stride-2 phase) on a remapped row.
__device__ __forceinline__ float4 hconv(const Row& w) {
    const float k0 = 0.0625f, k1 = 0.25f, k2 = 0.375f;
    float4 h;
    h.x = k0 * (w.A.z + w.B.z) + k1 * (w.A.w + w.B.y) + k2 * w.B.x;
    h.y = k0 * (w.B.x + w.C.x) + k1 * (w.B.y + w.B.w) + k2 * w.B.z;
    h.z = k0 * (w.B.z + w.C.z) + k1 * (w.B.w + w.C.y) + k2 * w.C.x;
    h.w = k0 * (w.C.x + w.D.x) + k1 * (w.C.y + w.C.w) + k2 * w.C.z;
    return h;
}

template <int R, int HIN, int WIN, bool FUSE>
__global__ __launch_bounds__(256) void gpyr_slide(
        const float* __restrict__ in,
        float* __restrict__ out0,
        float* __restrict__ out1) {
    constexpr int HOUT = HIN / 2, WOUT = WIN / 2;
    const int tx = threadIdx.x, ty = threadIdx.y;
    const int ox0 = (blockIdx.x * blockDim.x + tx) * 4;
    const int Y0  = (blockIdx.y * blockDim.y + ty) * R;
    const int img = blockIdx.z;

    const bool left  = (ox0 == 0);
    const bool right = (2 * ox0 + 12 > WIN);
    int xb = 2 * ox0 - 4;
    if (left)  xb = 0;
    if (right) xb = WIN - 16;

    const float* ip = in + (size_t)img * HIN * WIN;
    float* o1 = out1 + (size_t)img * HOUT * WOUT;
    float* o0 = out0 + (size_t)img * HIN * WIN;

    // Prologue rows + iteration-0 prefetch (all independent -> 5 loads in flight).
    Row r0 = loadrow<WIN>(ip, max(2 * Y0 - 2, 0), xb);
    Row r1 = loadrow<WIN>(ip, max(2 * Y0 - 1, 0), xb);
    Row r2 = loadrow<WIN>(ip, 2 * Y0, xb);
    Row ra = loadrow<WIN>(ip, 2 * Y0 + 1, xb);
    Row rb = loadrow<WIN>(ip, min(2 * Y0 + 2, HIN - 1), xb);

    remap(r0, left, right); remap(r1, left, right); remap(r2, left, right);
    float4 hs0 = hconv(r0), hs1 = hconv(r1), hs2 = hconv(r2);
    float4 qlo = r2.B, qhi = r2.C;   // pending copy data for even input row 2*Y0

    const float k0 = 0.0625f, k1 = 0.25f, k2 = 0.375f;

#pragma unroll
    for (int i = 0; i < R; ++i) {
        const int oy = Y0 + i;

        // Prefetch NEXT iteration's rows before consuming the current ones.
        Row ran, rbn;
        if (i + 1 < R) {
            ran = loadrow<WIN>(ip, 2 * (oy + 1) + 1, xb);                 // 2oy+3 <= HIN-1
            rbn = loadrow<WIN>(ip, min(2 * (oy + 1) + 2, HIN - 1), xb);
        }

        remap(ra, left, right);
        remap(rb, left, right);

        if (FUSE) {
            float* op = o0 + (size_t)(2 * oy) * WIN + 2 * ox0;
            *(float4*)(op)     = qlo;
            *(float4*)(op + 4) = qhi;
            float* op1 = o0 + (size_t)(2 * oy + 1) * WIN + 2 * ox0;
            *(float4*)(op1)     = ra.B;
            *(float4*)(op1 + 4) = ra.C;
        }

        float4 ha = hconv(ra), hb = hconv(rb);
        qlo = rb.B; qhi = rb.C;        // row 2*oy+2 = next iteration's even row

        float4 o;
        o.x = k0 * (hs0.x + hb.x) + k1 * (hs1.x + ha.x) + k2 * hs2.x;
        o.y = k0 * (hs0.y + hb.y) + k1 * (hs1.y + ha.y) + k2 * hs2.y;
        o.z = k0 * (hs0.z + hb.z) + k1 * (hs1.z + ha.z) + k2 * hs2.z;
        o.w = k0 * (hs0.w + hb.w) + k1 * (hs1.w + ha.w) + k2 * hs2.w;
        *(float4*)(o1 + (size_t)oy * WOUT + ox0) = o;

        hs0 = hs2; hs1 = ha; hs2 = hb;   // slide down 2 input rows
        ra = ran; rb = rbn;
    }
}

extern "C" void kernel_launch(void* const* d_in, const int* in_sizes, int n_in,
                              void* d_out, int out_size, void* d_ws, size_t ws_size,
                              hipStream_t stream) {
    const float* im = (const float*)d_in[0];
    float* out = (float*)d_out;

    const int NC = 16 * 3;
    const size_t L0 = (size_t)NC * 1024 * 1024;
    const size_t L1 = (size_t)NC * 512 * 512;
    const size_t L2 = (size_t)NC * 256 * 256;

    float* out0 = out;
    float* out1 = out0 + L0;
    float* out2 = out1 + L1;
    float* out3 = out2 + L2;

    // Level 0+1 fused: 512x512 out, R=8 rows/thread.
    {
        dim3 block(64, 4, 1);
        dim3 grid(2, 512 / (4 * 8), NC);       // (2, 16, 48)
        gpyr_slide<8, 1024, 1024, true><<<grid, block, 0, stream>>>(im, out0, out1);
    }
    // Level 2: 256x256 out, R=4.
    {
        dim3 block(64, 4, 1);
        dim3 grid(1, 256 / (4 * 4), NC);       // (1, 16, 48)
        gpyr_slide<4, 512, 512, false><<<grid, block, 0, stream>>>(out1, nullptr, out2);
    }
    // Level 3: 128x128 out, R=2.
    {
        dim3 block(32, 8, 1);
        dim3 grid(1, 128 / (8 * 2), NC);       // (1, 8, 48)
        gpyr_slide<2, 256, 256, false><<<grid, block, 0, stream>>>(out2, nullptr, out3);
    }
}